// Round 1
// baseline (1283.657 us; speedup 1.0000x reference)
//
#include <hip/hip_runtime.h>
#include <hip/hip_bf16.h>
#include <math.h>

// Problem constants
#define B_SZ 16
#define D_SZ 1024
#define R_SZ 100
#define DD (D_SZ * D_SZ)

// ---------------------------------------------------------------------------
// Kernel 1: Wsum[k,j] = (1/R) * sum_r gate_W[r,k,j]   (400MB read, BW-bound)
// ---------------------------------------------------------------------------
__global__ __launch_bounds__(256) void reduce_w_kernel(
    const float* __restrict__ gW, float* __restrict__ Wsum) {
    const int idx = blockIdx.x * blockDim.x + threadIdx.x;  // float4 index
    const float4* p = (const float4*)gW;
    float4 s = make_float4(0.f, 0.f, 0.f, 0.f);
#pragma unroll 4
    for (int r = 0; r < R_SZ; ++r) {
        float4 v = p[idx + r * (DD / 4)];
        s.x += v.x; s.y += v.y; s.z += v.z; s.w += v.w;
    }
    const float inv = 1.0f / (float)R_SZ;
    s.x *= inv; s.y *= inv; s.z *= inv; s.w *= inv;
    ((float4*)Wsum)[idx] = s;
}

// ---------------------------------------------------------------------------
// Kernel 2: bmean[k] = (1/R) * sum_r gate_b[r,k]
// ---------------------------------------------------------------------------
__global__ __launch_bounds__(256) void reduce_b_kernel(
    const float* __restrict__ gb, float* __restrict__ bmean) {
    const int k = blockIdx.x * blockDim.x + threadIdx.x;
    float s = 0.f;
#pragma unroll 4
    for (int r = 0; r < R_SZ; ++r) s += gb[r * D_SZ + k];
    bmean[k] = s * (1.0f / (float)R_SZ);
}

// ---------------------------------------------------------------------------
// Kernel 3: cosC = cos(phase), elementwise (1M elems, trivial)
// ---------------------------------------------------------------------------
__global__ __launch_bounds__(256) void cos_kernel(
    const float* __restrict__ ph, float* __restrict__ c) {
    const int i = blockIdx.x * blockDim.x + threadIdx.x;  // float4 index
    float4 v = ((const float4*)ph)[i];
    float4 o;
    o.x = cosf(v.x); o.y = cosf(v.y); o.z = cosf(v.z); o.w = cosf(v.w);
    ((float4*)c)[i] = o;
}

// ---------------------------------------------------------------------------
// Kernel 4: 32x32 LDS transpose (WsumT[j,k] = Wsum[k,j])
// ---------------------------------------------------------------------------
__global__ __launch_bounds__(256) void transpose_kernel(
    const float* __restrict__ in, float* __restrict__ out) {
    __shared__ float t[32][33];
    const int tx = threadIdx.x, ty = threadIdx.y;  // 32 x 8
    int x = blockIdx.x * 32 + tx;
    int y0 = blockIdx.y * 32;
#pragma unroll
    for (int j = 0; j < 32; j += 8) t[ty + j][tx] = in[(y0 + ty + j) * D_SZ + x];
    __syncthreads();
    int xo = blockIdx.y * 32 + tx;
    int yo = blockIdx.x * 32;
#pragma unroll
    for (int j = 0; j < 32; j += 8) out[(yo + ty + j) * D_SZ + xo] = t[tx][ty + j];
}

// ---------------------------------------------------------------------------
// Kernel 5: generic fp32 SGEMM, C = A @ B, N=1024 square, 128x128 tile,
// 256 threads, 8x8 micro-tile per thread (quadrant split -> conflict-free LDS)
// ---------------------------------------------------------------------------
#define TS 128
#define KB 8

__global__ __launch_bounds__(256) void sgemm_nn_kernel(
    const float* __restrict__ A, const float* __restrict__ Bm,
    float* __restrict__ C) {
    __shared__ float As[KB][TS];
    __shared__ float Bs[KB][TS];
    const int tid = threadIdx.x;
    const int tx = tid & 15, ty = tid >> 4;
    const int brow = blockIdx.y * TS, bcol = blockIdx.x * TS;
    // staging indices
    const int ar = tid >> 1, ac = (tid & 1) * 4;     // A: 128 rows x 8 cols
    const int br = tid >> 5, bc = (tid & 31) * 4;    // B: 8 rows x 128 cols
    float acc[8][8] = {};
    for (int k0 = 0; k0 < D_SZ; k0 += KB) {
        float4 av = *(const float4*)&A[(brow + ar) * D_SZ + k0 + ac];
        float4 bv = *(const float4*)&Bm[(k0 + br) * D_SZ + bcol + bc];
        __syncthreads();
        As[ac + 0][ar] = av.x; As[ac + 1][ar] = av.y;
        As[ac + 2][ar] = av.z; As[ac + 3][ar] = av.w;
        *(float4*)&Bs[br][bc] = bv;
        __syncthreads();
#pragma unroll
        for (int kk = 0; kk < KB; ++kk) {
            float4 a0 = *(const float4*)&As[kk][ty * 4];
            float4 a1 = *(const float4*)&As[kk][64 + ty * 4];
            float4 b0 = *(const float4*)&Bs[kk][tx * 4];
            float4 b1 = *(const float4*)&Bs[kk][64 + tx * 4];
            float am[8] = {a0.x, a0.y, a0.z, a0.w, a1.x, a1.y, a1.z, a1.w};
            float bn[8] = {b0.x, b0.y, b0.z, b0.w, b1.x, b1.y, b1.z, b1.w};
#pragma unroll
            for (int m = 0; m < 8; ++m)
#pragma unroll
                for (int n = 0; n < 8; ++n) acc[m][n] += am[m] * bn[n];
        }
    }
#pragma unroll
    for (int m = 0; m < 8; ++m) {
        int r = brow + ((m < 4) ? (ty * 4 + m) : (64 + ty * 4 + (m - 4)));
        float4 v0 = make_float4(acc[m][0], acc[m][1], acc[m][2], acc[m][3]);
        float4 v1 = make_float4(acc[m][4], acc[m][5], acc[m][6], acc[m][7]);
        *(float4*)&C[r * D_SZ + bcol + tx * 4] = v0;
        *(float4*)&C[r * D_SZ + bcol + 64 + tx * 4] = v1;
    }
}

// ---------------------------------------------------------------------------
// Kernel 6: batched output GEMM.
//   out[b] = (cosC * x[b] (col-scaled)) @ M + bmean   for b = blockIdx.z
// Same structure as sgemm_nn; A elements scaled on load by x[b, l].
// ---------------------------------------------------------------------------
__global__ __launch_bounds__(256) void batched_out_kernel(
    const float* __restrict__ cosC, const float* __restrict__ x,
    const float* __restrict__ M, const float* __restrict__ bmean,
    float* __restrict__ out) {
    __shared__ float As[KB][TS];
    __shared__ float Bs[KB][TS];
    const int tid = threadIdx.x;
    const int tx = tid & 15, ty = tid >> 4;
    const int brow = blockIdx.y * TS, bcol = blockIdx.x * TS;
    const int b = blockIdx.z;
    const float* xb = x + b * D_SZ;
    float* outb = out + (size_t)b * DD;
    const int ar = tid >> 1, ac = (tid & 1) * 4;
    const int br = tid >> 5, bc = (tid & 31) * 4;
    float acc[8][8] = {};
    for (int k0 = 0; k0 < D_SZ; k0 += KB) {
        float4 av = *(const float4*)&cosC[(brow + ar) * D_SZ + k0 + ac];
        float4 xv = *(const float4*)&xb[k0 + ac];
        av.x *= xv.x; av.y *= xv.y; av.z *= xv.z; av.w *= xv.w;
        float4 bv = *(const float4*)&M[(k0 + br) * D_SZ + bcol + bc];
        __syncthreads();
        As[ac + 0][ar] = av.x; As[ac + 1][ar] = av.y;
        As[ac + 2][ar] = av.z; As[ac + 3][ar] = av.w;
        *(float4*)&Bs[br][bc] = bv;
        __syncthreads();
#pragma unroll
        for (int kk = 0; kk < KB; ++kk) {
            float4 a0 = *(const float4*)&As[kk][ty * 4];
            float4 a1 = *(const float4*)&As[kk][64 + ty * 4];
            float4 b0 = *(const float4*)&Bs[kk][tx * 4];
            float4 b1 = *(const float4*)&Bs[kk][64 + tx * 4];
            float am[8] = {a0.x, a0.y, a0.z, a0.w, a1.x, a1.y, a1.z, a1.w};
            float bn[8] = {b0.x, b0.y, b0.z, b0.w, b1.x, b1.y, b1.z, b1.w};
#pragma unroll
            for (int m = 0; m < 8; ++m)
#pragma unroll
                for (int n = 0; n < 8; ++n) acc[m][n] += am[m] * bn[n];
        }
    }
    float4 bm0 = *(const float4*)&bmean[bcol + tx * 4];
    float4 bm1 = *(const float4*)&bmean[bcol + 64 + tx * 4];
#pragma unroll
    for (int m = 0; m < 8; ++m) {
        int r = brow + ((m < 4) ? (ty * 4 + m) : (64 + ty * 4 + (m - 4)));
        float4 v0 = make_float4(acc[m][0] + bm0.x, acc[m][1] + bm0.y,
                                acc[m][2] + bm0.z, acc[m][3] + bm0.w);
        float4 v1 = make_float4(acc[m][4] + bm1.x, acc[m][5] + bm1.y,
                                acc[m][6] + bm1.z, acc[m][7] + bm1.w);
        *(float4*)&outb[(size_t)r * D_SZ + bcol + tx * 4] = v0;
        *(float4*)&outb[(size_t)r * D_SZ + bcol + 64 + tx * 4] = v1;
    }
}

// ---------------------------------------------------------------------------
// Launch. Workspace layout (floats):
//   cosC [0, 1M) | Wsum [1M, 2M) | WsumT [2M, 3M) | P [3M, 4M) | M [4M, 5M)
//   bmean [5M, 5M+1024)        total ~20 MB
// ---------------------------------------------------------------------------
extern "C" void kernel_launch(void* const* d_in, const int* in_sizes, int n_in,
                              void* d_out, int out_size, void* d_ws, size_t ws_size,
                              hipStream_t stream) {
    const float* x  = (const float*)d_in[0];  // (16,1,1024)
    const float* qw = (const float*)d_in[1];  // (1024,1024)
    const float* qp = (const float*)d_in[2];  // (1024,1024)
    const float* em = (const float*)d_in[3];  // (1024,1024)
    const float* gW = (const float*)d_in[4];  // (100,1024,1024)
    const float* gb = (const float*)d_in[5];  // (100,1024)
    float* out = (float*)d_out;               // (16,1024,1024)

    float* ws    = (float*)d_ws;
    float* cosC  = ws;
    float* Wsum  = ws + (1 << 20);
    float* WsumT = ws + 2 * (1 << 20);
    float* P     = ws + 3 * (1 << 20);
    float* M     = ws + 4 * (1 << 20);
    float* bmean = ws + 5 * (1 << 20);

    // Stage 1: reductions + cos (independent)
    reduce_w_kernel<<<DD / 4 / 256, 256, 0, stream>>>(gW, Wsum);
    reduce_b_kernel<<<D_SZ / 256, 256, 0, stream>>>(gb, bmean);
    cos_kernel<<<DD / 4 / 256, 256, 0, stream>>>(qp, cosC);
    // Stage 2: transpose Wsum -> WsumT
    transpose_kernel<<<dim3(32, 32), dim3(32, 8), 0, stream>>>(Wsum, WsumT);
    // Stage 3: P = QW @ E ;  M = P @ WsumT
    sgemm_nn_kernel<<<dim3(8, 8), 256, 0, stream>>>(qw, em, P);
    sgemm_nn_kernel<<<dim3(8, 8), 256, 0, stream>>>(P, WsumT, M);
    // Stage 4: out[b] = (cosC col-scaled by x[b]) @ M + bmean
    batched_out_kernel<<<dim3(8, 8, B_SZ), 256, 0, stream>>>(cosC, x, M, bmean, out);
}

// Round 2
// 685.044 us; speedup vs baseline: 1.8738x; 1.8738x over previous
//
#include <hip/hip_runtime.h>
#include <hip/hip_fp16.h>
#include <math.h>

#define B_SZ 16
#define D 1024
#define R_SZ 100
#define DD (D * D)

typedef _Float16 half8 __attribute__((ext_vector_type(8)));
typedef _Float16 half4v __attribute__((ext_vector_type(4)));
typedef float float4v __attribute__((ext_vector_type(4)));

// ---------------------------------------------------------------------------
// Wsumh[k,j] = fp16( (1/R) * sum_r gate_W[r,k,j] )   (400MB read, BW-bound)
// ---------------------------------------------------------------------------
__global__ __launch_bounds__(256) void reduce_w_kernel(
    const float* __restrict__ gW, _Float16* __restrict__ Wsumh) {
    const int idx = blockIdx.x * blockDim.x + threadIdx.x;  // float4 index
    const float4* p = (const float4*)gW;
    float4 s = make_float4(0.f, 0.f, 0.f, 0.f);
#pragma unroll 4
    for (int r = 0; r < R_SZ; ++r) {
        float4 v = p[idx + r * (DD / 4)];
        s.x += v.x; s.y += v.y; s.z += v.z; s.w += v.w;
    }
    const float inv = 1.0f / (float)R_SZ;
    half4v h;
    h[0] = (_Float16)(s.x * inv); h[1] = (_Float16)(s.y * inv);
    h[2] = (_Float16)(s.z * inv); h[3] = (_Float16)(s.w * inv);
    *(half4v*)&Wsumh[idx * 4] = h;
}

// ---------------------------------------------------------------------------
// bmean[k] = (1/R) * sum_r gate_b[r,k]   (fp32, fused into G3 epilogue)
// ---------------------------------------------------------------------------
__global__ __launch_bounds__(256) void reduce_b_kernel(
    const float* __restrict__ gb, float* __restrict__ bmean) {
    const int k = blockIdx.x * blockDim.x + threadIdx.x;
    float s = 0.f;
#pragma unroll 4
    for (int r = 0; r < R_SZ; ++r) s += gb[r * D + k];
    bmean[k] = s * (1.0f / (float)R_SZ);
}

// ---------------------------------------------------------------------------
// Elementwise converts
// ---------------------------------------------------------------------------
__global__ __launch_bounds__(256) void cvt_f2h_kernel(
    const float* __restrict__ in, _Float16* __restrict__ out) {
    const int i = blockIdx.x * blockDim.x + threadIdx.x;  // float4 index
    float4 v = ((const float4*)in)[i];
    half4v h;
    h[0] = (_Float16)v.x; h[1] = (_Float16)v.y;
    h[2] = (_Float16)v.z; h[3] = (_Float16)v.w;
    *(half4v*)&out[i * 4] = h;
}

__global__ __launch_bounds__(256) void cos_h_kernel(
    const float* __restrict__ ph, _Float16* __restrict__ out) {
    const int i = blockIdx.x * blockDim.x + threadIdx.x;  // float4 index
    float4 v = ((const float4*)ph)[i];
    half4v h;
    h[0] = (_Float16)cosf(v.x); h[1] = (_Float16)cosf(v.y);
    h[2] = (_Float16)cosf(v.z); h[3] = (_Float16)cosf(v.w);
    *(half4v*)&out[i * 4] = h;
}

__global__ __launch_bounds__(256) void cvt_x_kernel(
    const float* __restrict__ x, _Float16* __restrict__ xh) {
    const int i = blockIdx.x * blockDim.x + threadIdx.x;
    xh[i] = (_Float16)x[i];
}

// ---------------------------------------------------------------------------
// ETh[j][t] = fp16( em[t][j] )  — 32x32 LDS transpose + convert
// ---------------------------------------------------------------------------
__global__ __launch_bounds__(256) void tcvt_kernel(
    const float* __restrict__ in, _Float16* __restrict__ out) {
    __shared__ float t[32][33];
    const int tx = threadIdx.x, ty = threadIdx.y;  // 32 x 8
    int x = blockIdx.x * 32 + tx;
    int y0 = blockIdx.y * 32;
#pragma unroll
    for (int j = 0; j < 32; j += 8) t[ty + j][tx] = in[(y0 + ty + j) * D + x];
    __syncthreads();
    int xo = blockIdx.y * 32 + tx;
    int yo = blockIdx.x * 32;
#pragma unroll
    for (int j = 0; j < 32; j += 8)
        out[(yo + ty + j) * D + xo] = (_Float16)t[tx][ty + j];
}

// ---------------------------------------------------------------------------
// MFMA GEMM: C = A @ BT^T  (A [M][K], BT [N][K], both fp16 row-major, K=D)
// m97 structure: 128x128 tile, BK=32, 4 waves, global_load_lds width 16,
// v_mfma_f32_16x16x32_f16, 4x4 fragments per wave.
// SCALE_BIAS: B-frag scaled by xh[batch][k] on the fly; +bias; fp32 out.
// ---------------------------------------------------------------------------
template <bool SCALE_BIAS>
__global__ __launch_bounds__(256) void mfma_gemm_bt(
    const _Float16* __restrict__ A, const _Float16* __restrict__ BT,
    const _Float16* __restrict__ xh, const float* __restrict__ bias,
    void* __restrict__ Cout) {
    __shared__ __align__(16) _Float16 As[128 * 32];
    __shared__ __align__(16) _Float16 Bs[128 * 32];
    const int tid = threadIdx.x;
    const int wid = tid >> 6;
    const int lane = tid & 63;
    const int brow = blockIdx.y * 128;
    const int bcol = blockIdx.x * 128;
    const int batch = SCALE_BIAS ? blockIdx.z : 0;
    const _Float16* xb = SCALE_BIAS ? (xh + batch * D) : (const _Float16*)nullptr;

    // staging geometry: inst chunk = 4KB = 64 rows x 64B; thread slot = 16B
    const int s_r = tid >> 2;          // row within 64-row chunk
    const int s_k = (tid & 3) * 8;     // k offset in halves
    // fragment geometry
    const int wr = wid >> 1, wc = wid & 1;          // wave quadrant (2x2)
    const int fr = lane & 15;                       // A/B frag row
    const int fk = (lane >> 4) * 8;                 // frag k base

    float4v acc[4][4] = {};

    for (int k0 = 0; k0 < D; k0 += 32) {
        __syncthreads();  // prior iter done reading LDS
        const _Float16* ga0 = A + (size_t)(brow + s_r) * D + k0 + s_k;
        const _Float16* ga1 = A + (size_t)(brow + 64 + s_r) * D + k0 + s_k;
        const _Float16* gb0 = BT + (size_t)(bcol + s_r) * D + k0 + s_k;
        const _Float16* gb1 = BT + (size_t)(bcol + 64 + s_r) * D + k0 + s_k;
        __builtin_amdgcn_global_load_lds(
            (const __attribute__((address_space(1))) void*)ga0,
            (__attribute__((address_space(3))) void*)(As + wid * 512), 16, 0, 0);
        __builtin_amdgcn_global_load_lds(
            (const __attribute__((address_space(1))) void*)ga1,
            (__attribute__((address_space(3))) void*)(As + 2048 + wid * 512), 16, 0, 0);
        __builtin_amdgcn_global_load_lds(
            (const __attribute__((address_space(1))) void*)gb0,
            (__attribute__((address_space(3))) void*)(Bs + wid * 512), 16, 0, 0);
        __builtin_amdgcn_global_load_lds(
            (const __attribute__((address_space(1))) void*)gb1,
            (__attribute__((address_space(3))) void*)(Bs + 2048 + wid * 512), 16, 0, 0);
        __syncthreads();  // vmcnt(0) drained by compiler before barrier

        half8 xf;
        if constexpr (SCALE_BIAS) xf = *(const half8*)&xb[k0 + fk];
        half8 a[4], b[4];
#pragma unroll
        for (int m = 0; m < 4; ++m)
            a[m] = *(const half8*)&As[(wr * 64 + m * 16 + fr) * 32 + fk];
#pragma unroll
        for (int n = 0; n < 4; ++n) {
            b[n] = *(const half8*)&Bs[(wc * 64 + n * 16 + fr) * 32 + fk];
            if constexpr (SCALE_BIAS) b[n] = b[n] * xf;
        }
#pragma unroll
        for (int m = 0; m < 4; ++m)
#pragma unroll
            for (int n = 0; n < 4; ++n)
                acc[m][n] = __builtin_amdgcn_mfma_f32_16x16x32_f16(
                    a[m], b[n], acc[m][n], 0, 0, 0);
    }

    // epilogue — C/D layout: col = lane&15, row = (lane>>4)*4 + reg
    const int crow = (lane >> 4) * 4;
    const int ccol = lane & 15;
    if constexpr (SCALE_BIAS) {
        float* outb = (float*)Cout + (size_t)batch * DD;
#pragma unroll
        for (int n = 0; n < 4; ++n) {
            const int gn = bcol + wc * 64 + n * 16 + ccol;
            const float bm = bias[gn];
#pragma unroll
            for (int m = 0; m < 4; ++m) {
                const int gm0 = brow + wr * 64 + m * 16 + crow;
#pragma unroll
                for (int r = 0; r < 4; ++r)
                    outb[(size_t)(gm0 + r) * D + gn] = acc[m][n][r] + bm;
            }
        }
    } else {
        _Float16* outh = (_Float16*)Cout;
#pragma unroll
        for (int n = 0; n < 4; ++n) {
            const int gn = bcol + wc * 64 + n * 16 + ccol;
#pragma unroll
            for (int m = 0; m < 4; ++m) {
                const int gm0 = brow + wr * 64 + m * 16 + crow;
#pragma unroll
                for (int r = 0; r < 4; ++r)
                    outh[(size_t)(gm0 + r) * D + gn] = (_Float16)acc[m][n][r];
            }
        }
    }
}

// ---------------------------------------------------------------------------
// Launch. Workspace (halves unless noted):
//   QWh [0,1M) | ETh [1M,2M) | cosCh [2M,3M) | Wsumh [3M,4M)
//   Ph [4M,5M) | MTh [5M,6M) | xh [6M,6M+16K) | bmean fp32 after
// ---------------------------------------------------------------------------
extern "C" void kernel_launch(void* const* d_in, const int* in_sizes, int n_in,
                              void* d_out, int out_size, void* d_ws, size_t ws_size,
                              hipStream_t stream) {
    const float* x  = (const float*)d_in[0];  // (16,1,1024)
    const float* qw = (const float*)d_in[1];  // (1024,1024)
    const float* qp = (const float*)d_in[2];  // (1024,1024)
    const float* em = (const float*)d_in[3];  // (1024,1024)
    const float* gW = (const float*)d_in[4];  // (100,1024,1024)
    const float* gb = (const float*)d_in[5];  // (100,1024)
    float* out = (float*)d_out;               // (16,1024,1024)

    _Float16* h = (_Float16*)d_ws;
    _Float16* QWh   = h;
    _Float16* ETh   = h + (1 << 20);
    _Float16* cosCh = h + 2 * (1 << 20);
    _Float16* Wsumh = h + 3 * (1 << 20);
    _Float16* Ph    = h + 4 * (1 << 20);
    _Float16* MTh   = h + 5 * (1 << 20);
    _Float16* xh    = h + 6 * (1 << 20);
    float* bmean    = (float*)(h + 6 * (1 << 20) + 32768);

    // Stage 1: reductions + converts (independent)
    reduce_w_kernel<<<DD / 4 / 256, 256, 0, stream>>>(gW, Wsumh);
    reduce_b_kernel<<<D / 256, 256, 0, stream>>>(gb, bmean);
    cvt_f2h_kernel<<<DD / 4 / 256, 256, 0, stream>>>(qw, QWh);
    cos_h_kernel<<<DD / 4 / 256, 256, 0, stream>>>(qp, cosCh);
    tcvt_kernel<<<dim3(32, 32), dim3(32, 8), 0, stream>>>(em, ETh);
    cvt_x_kernel<<<B_SZ * D / 256, 256, 0, stream>>>(x, xh);
    // Stage 2: P[l][j] = sum_t QW[l,t] * E^T[j,t]
    mfma_gemm_bt<false><<<dim3(8, 8), 256, 0, stream>>>(QWh, ETh, nullptr, nullptr, Ph);
    // Stage 3: MT[k][l] = sum_j Wsum[k,j] * P[l,j]
    mfma_gemm_bt<false><<<dim3(8, 8), 256, 0, stream>>>(Wsumh, Ph, nullptr, nullptr, MTh);
    // Stage 4: out[b][i,k] = sum_l cosC[i,l] * x_b[l] * MT[k,l] + bmean[k]
    mfma_gemm_bt<true><<<dim3(8, 8, B_SZ), 256, 0, stream>>>(cosCh, MTh, xh, bmean, out);
}

// Round 3
// 664.538 us; speedup vs baseline: 1.9317x; 1.0309x over previous
//
#include <hip/hip_runtime.h>
#include <hip/hip_fp16.h>
#include <math.h>

#define B_SZ 16
#define D 1024
#define R_SZ 100
#define DD (D * D)

typedef _Float16 half8 __attribute__((ext_vector_type(8)));
typedef _Float16 half4v __attribute__((ext_vector_type(4)));
typedef float float4v __attribute__((ext_vector_type(4)));

// ---------------------------------------------------------------------------
// Fused converts: QW->h | cos(phase)->h | E^T->h | x->h | bmean
// One heterogeneous dispatch; all independent elementwise work.
//   blocks [0,1024)    : QWh[i]   = (h) qw[i]
//   blocks [1024,2048) : cosCh[i] = (h) cos(qp[i])
//   blocks [2048,3072) : ETh[j][t] = (h) em[t][j]   (32x32 LDS transpose)
//   blocks [3072,3088) : xh = (h) x
//   blocks [3088,3092) : bmean[k] = mean_r gb[r,k]  (fp32)
// ---------------------------------------------------------------------------
__global__ __launch_bounds__(256) void fused_cvt_kernel(
    const float* __restrict__ qw, const float* __restrict__ qp,
    const float* __restrict__ em, const float* __restrict__ x,
    const float* __restrict__ gb,
    _Float16* __restrict__ QWh, _Float16* __restrict__ cosCh,
    _Float16* __restrict__ ETh, _Float16* __restrict__ xh,
    float* __restrict__ bmean) {
    __shared__ float t[32][33];
    const int blk = blockIdx.x, tid = threadIdx.x;
    if (blk < 1024) {
        const int i = blk * 256 + tid;
        float4 v = ((const float4*)qw)[i];
        half4v h;
        h[0] = (_Float16)v.x; h[1] = (_Float16)v.y;
        h[2] = (_Float16)v.z; h[3] = (_Float16)v.w;
        *(half4v*)&QWh[i * 4] = h;
    } else if (blk < 2048) {
        const int i = (blk - 1024) * 256 + tid;
        float4 v = ((const float4*)qp)[i];
        half4v h;
        h[0] = (_Float16)cosf(v.x); h[1] = (_Float16)cosf(v.y);
        h[2] = (_Float16)cosf(v.z); h[3] = (_Float16)cosf(v.w);
        *(half4v*)&cosCh[i * 4] = h;
    } else if (blk < 3072) {
        const int local = blk - 2048;
        const int bx = local & 31, by = local >> 5;
        const int tx = tid & 31, ty = tid >> 5;  // 32 x 8
#pragma unroll
        for (int j = 0; j < 32; j += 8)
            t[ty + j][tx] = em[(by * 32 + ty + j) * D + bx * 32 + tx];
        __syncthreads();
#pragma unroll
        for (int j = 0; j < 32; j += 8)
            ETh[(size_t)(bx * 32 + ty + j) * D + by * 32 + tx] =
                (_Float16)t[tx][ty + j];
    } else if (blk < 3088) {
        const int i = (blk - 3072) * 256 + tid;  // float4 index, 4096 total
        float4 v = ((const float4*)x)[i];
        half4v h;
        h[0] = (_Float16)v.x; h[1] = (_Float16)v.y;
        h[2] = (_Float16)v.z; h[3] = (_Float16)v.w;
        *(half4v*)&xh[i * 4] = h;
    } else {
        const int k = (blk - 3088) * 256 + tid;
        float s = 0.f;
#pragma unroll 4
        for (int r = 0; r < R_SZ; ++r) s += gb[r * D + k];
        bmean[k] = s * (1.0f / (float)R_SZ);
    }
}

// ---------------------------------------------------------------------------
// 64x64-tile MFMA GEMM body: C = A @ BT^T (fp16 in, fp16 out), K = D.
// 256 threads / 4 waves, each wave a 32x32 quadrant, BK=32.
// ---------------------------------------------------------------------------
__device__ __forceinline__ void gemm64_body(
    const _Float16* __restrict__ A, const _Float16* __restrict__ BT,
    _Float16* __restrict__ C, int bid, int tid,
    _Float16* As, _Float16* Bs) {
    const int wid = tid >> 6, lane = tid & 63;
    const int brow = (bid >> 4) * 64, bcol = (bid & 15) * 64;
    const int s_r = tid >> 2, s_k = (tid & 3) * 8;   // 64 rows x 4x16B
    const int wr = wid >> 1, wc = wid & 1;
    const int fr = lane & 15, fk = (lane >> 4) * 8;
    float4v acc[2][2] = {};
    for (int k0 = 0; k0 < D; k0 += 32) {
        __syncthreads();
        const _Float16* ga = A + (size_t)(brow + s_r) * D + k0 + s_k;
        const _Float16* gbp = BT + (size_t)(bcol + s_r) * D + k0 + s_k;
        __builtin_amdgcn_global_load_lds(
            (const __attribute__((address_space(1))) void*)ga,
            (__attribute__((address_space(3))) void*)(As + wid * 512), 16, 0, 0);
        __builtin_amdgcn_global_load_lds(
            (const __attribute__((address_space(1))) void*)gbp,
            (__attribute__((address_space(3))) void*)(Bs + wid * 512), 16, 0, 0);
        __syncthreads();
        half8 a[2], b[2];
        a[0] = *(const half8*)&As[(wr * 32 + fr) * 32 + fk];
        a[1] = *(const half8*)&As[(wr * 32 + 16 + fr) * 32 + fk];
        b[0] = *(const half8*)&Bs[(wc * 32 + fr) * 32 + fk];
        b[1] = *(const half8*)&Bs[(wc * 32 + 16 + fr) * 32 + fk];
#pragma unroll
        for (int m = 0; m < 2; ++m)
#pragma unroll
            for (int n = 0; n < 2; ++n)
                acc[m][n] = __builtin_amdgcn_mfma_f32_16x16x32_f16(
                    a[m], b[n], acc[m][n], 0, 0, 0);
    }
    const int crow = (lane >> 4) * 4, ccol = lane & 15;
#pragma unroll
    for (int n = 0; n < 2; ++n) {
        const int gn = bcol + wc * 32 + n * 16 + ccol;
#pragma unroll
        for (int m = 0; m < 2; ++m) {
            const int gm0 = brow + wr * 32 + m * 16 + crow;
#pragma unroll
            for (int r = 0; r < 4; ++r)
                C[(size_t)(gm0 + r) * D + gn] = (_Float16)acc[m][n][r];
        }
    }
}

// ---------------------------------------------------------------------------
// Mega dispatch: blocks [0,256) = P gemm (MFMA-bound), blocks [256,1280)
// = reduce_w (BW-bound). The two co-schedule on the CUs (MFMA pipe vs HBM),
// so P rides inside reduce_w's ~64us memory shadow.
//   P[l][j]   = sum_t QW[l,t]*E^T[j,t]
//   Wsumh[k,j]= (h)( mean_r gate_W[r,k,j] )
// ---------------------------------------------------------------------------
__global__ __launch_bounds__(256) void mega_pw_kernel(
    const _Float16* __restrict__ QWh, const _Float16* __restrict__ ETh,
    _Float16* __restrict__ Ph,
    const float* __restrict__ gW, _Float16* __restrict__ Wsumh) {
    __shared__ __align__(16) _Float16 As[64 * 32];
    __shared__ __align__(16) _Float16 Bs[64 * 32];
    const int tid = threadIdx.x;
    if (blockIdx.x < 256) {
        gemm64_body(QWh, ETh, Ph, blockIdx.x, tid, As, Bs);
    } else {
        const int idx = (blockIdx.x - 256) * 256 + tid;  // float4 index
        const float4* p = (const float4*)gW;
        float4 s = make_float4(0.f, 0.f, 0.f, 0.f);
#pragma unroll 4
        for (int r = 0; r < R_SZ; ++r) {
            float4 v = p[idx + r * (DD / 4)];
            s.x += v.x; s.y += v.y; s.z += v.z; s.w += v.w;
        }
        const float inv = 1.0f / (float)R_SZ;
        half4v h;
        h[0] = (_Float16)(s.x * inv); h[1] = (_Float16)(s.y * inv);
        h[2] = (_Float16)(s.z * inv); h[3] = (_Float16)(s.w * inv);
        *(half4v*)&Wsumh[idx * 4] = h;
    }
}

// ---------------------------------------------------------------------------
// MT[k][l] = sum_j Wsum[k,j] * P[l,j]   (64x64 tile, 256 blocks)
// ---------------------------------------------------------------------------
__global__ __launch_bounds__(256) void gemm64_kernel(
    const _Float16* __restrict__ A, const _Float16* __restrict__ BT,
    _Float16* __restrict__ C) {
    __shared__ __align__(16) _Float16 As[64 * 32];
    __shared__ __align__(16) _Float16 Bs[64 * 32];
    gemm64_body(A, BT, C, blockIdx.x, threadIdx.x, As, Bs);
}

// ---------------------------------------------------------------------------
// Batched output GEMM (unchanged from R2, proven):
//   out[b][i,k] = sum_l cosC[i,l] * x_b[l] * MT[k,l] + bmean[k]
// 128x128 tile, BK=32, 4 waves, 4x4 frags, B-frag scaled by xh on the fly.
// ---------------------------------------------------------------------------
__global__ __launch_bounds__(256) void batched_out_kernel(
    const _Float16* __restrict__ A, const _Float16* __restrict__ BT,
    const _Float16* __restrict__ xh, const float* __restrict__ bias,
    float* __restrict__ Cout) {
    __shared__ __align__(16) _Float16 As[128 * 32];
    __shared__ __align__(16) _Float16 Bs[128 * 32];
    const int tid = threadIdx.x;
    const int wid = tid >> 6;
    const int lane = tid & 63;
    const int brow = blockIdx.y * 128;
    const int bcol = blockIdx.x * 128;
    const int batch = blockIdx.z;
    const _Float16* xb = xh + batch * D;

    const int s_r = tid >> 2;
    const int s_k = (tid & 3) * 8;
    const int wr = wid >> 1, wc = wid & 1;
    const int fr = lane & 15;
    const int fk = (lane >> 4) * 8;

    float4v acc[4][4] = {};

    for (int k0 = 0; k0 < D; k0 += 32) {
        __syncthreads();
        const _Float16* ga0 = A + (size_t)(brow + s_r) * D + k0 + s_k;
        const _Float16* ga1 = A + (size_t)(brow + 64 + s_r) * D + k0 + s_k;
        const _Float16* gb0 = BT + (size_t)(bcol + s_r) * D + k0 + s_k;
        const _Float16* gb1 = BT + (size_t)(bcol + 64 + s_r) * D + k0 + s_k;
        __builtin_amdgcn_global_load_lds(
            (const __attribute__((address_space(1))) void*)ga0,
            (__attribute__((address_space(3))) void*)(As + wid * 512), 16, 0, 0);
        __builtin_amdgcn_global_load_lds(
            (const __attribute__((address_space(1))) void*)ga1,
            (__attribute__((address_space(3))) void*)(As + 2048 + wid * 512), 16, 0, 0);
        __builtin_amdgcn_global_load_lds(
            (const __attribute__((address_space(1))) void*)gb0,
            (__attribute__((address_space(3))) void*)(Bs + wid * 512), 16, 0, 0);
        __builtin_amdgcn_global_load_lds(
            (const __attribute__((address_space(1))) void*)gb1,
            (__attribute__((address_space(3))) void*)(Bs + 2048 + wid * 512), 16, 0, 0);
        __syncthreads();

        half8 xf = *(const half8*)&xb[k0 + fk];
        half8 a[4], b[4];
#pragma unroll
        for (int m = 0; m < 4; ++m)
            a[m] = *(const half8*)&As[(wr * 64 + m * 16 + fr) * 32 + fk];
#pragma unroll
        for (int n = 0; n < 4; ++n) {
            b[n] = *(const half8*)&Bs[(wc * 64 + n * 16 + fr) * 32 + fk];
            b[n] = b[n] * xf;
        }
#pragma unroll
        for (int m = 0; m < 4; ++m)
#pragma unroll
            for (int n = 0; n < 4; ++n)
                acc[m][n] = __builtin_amdgcn_mfma_f32_16x16x32_f16(
                    a[m], b[n], acc[m][n], 0, 0, 0);
    }

    const int crow = (lane >> 4) * 4;
    const int ccol = lane & 15;
    float* outb = Cout + (size_t)batch * DD;
#pragma unroll
    for (int n = 0; n < 4; ++n) {
        const int gn = bcol + wc * 64 + n * 16 + ccol;
        const float bm = bias[gn];
#pragma unroll
        for (int m = 0; m < 4; ++m) {
            const int gm0 = brow + wr * 64 + m * 16 + crow;
#pragma unroll
            for (int r = 0; r < 4; ++r)
                outb[(size_t)(gm0 + r) * D + gn] = acc[m][n][r] + bm;
        }
    }
}

// ---------------------------------------------------------------------------
// Launch. Workspace (halves):
//   QWh 0 | ETh 1M | cosCh 2M | Wsumh 3M | Ph 4M | MTh 5M | xh 6M | bmean
// ---------------------------------------------------------------------------
extern "C" void kernel_launch(void* const* d_in, const int* in_sizes, int n_in,
                              void* d_out, int out_size, void* d_ws, size_t ws_size,
                              hipStream_t stream) {
    const float* x  = (const float*)d_in[0];
    const float* qw = (const float*)d_in[1];
    const float* qp = (const float*)d_in[2];
    const float* em = (const float*)d_in[3];
    const float* gW = (const float*)d_in[4];
    const float* gb = (const float*)d_in[5];
    float* out = (float*)d_out;

    _Float16* h = (_Float16*)d_ws;
    _Float16* QWh   = h;
    _Float16* ETh   = h + (1 << 20);
    _Float16* cosCh = h + 2 * (1 << 20);
    _Float16* Wsumh = h + 3 * (1 << 20);
    _Float16* Ph    = h + 4 * (1 << 20);
    _Float16* MTh   = h + 5 * (1 << 20);
    _Float16* xh    = h + 6 * (1 << 20);
    float* bmean    = (float*)(h + 6 * (1 << 20) + 32768);

    // 1. all converts + bias mean, one dispatch
    fused_cvt_kernel<<<3092, 256, 0, stream>>>(qw, qp, em, x, gb,
                                               QWh, cosCh, ETh, xh, bmean);
    // 2. P gemm (256 blks, MFMA) + reduce_w (1024 blks, HBM) co-scheduled
    mega_pw_kernel<<<1280, 256, 0, stream>>>(QWh, ETh, Ph, gW, Wsumh);
    // 3. MT[k][l] = sum_j Wsum[k,j] * P[l,j]
    gemm64_kernel<<<256, 256, 0, stream>>>(Wsumh, Ph, MTh);
    // 4. out[b] = (cosC . x_b) @ MT^T + bmean
    batched_out_kernel<<<dim3(8, 8, B_SZ), 256, 0, stream>>>(cosCh, MTh, xh, bmean, out);
}